// Round 3
// baseline (300.351 us; speedup 1.0000x reference)
//
#include <hip/hip_runtime.h>

typedef unsigned short u16;
typedef __attribute__((ext_vector_type(4))) float f32x4;
typedef __attribute__((ext_vector_type(8))) short bf16x8;

#define MFMA16(a, b, c) __builtin_amdgcn_mfma_f32_16x16x32_bf16(a, b, c, 0, 0, 0)

// fp32 -> bf16 round-to-nearest-even (finite inputs only)
__device__ __forceinline__ u16 f2bf(float f) {
    union { float f; unsigned u; } v;
    v.f = f;
    unsigned r = v.u + 0x7FFFu + ((v.u >> 16) & 1u);
    return (u16)(r >> 16);
}

__device__ __forceinline__ int4 pack8(const float4 a, const float4 b) {
    int4 r;
    r.x = (int)((unsigned)f2bf(a.x) | ((unsigned)f2bf(a.y) << 16));
    r.y = (int)((unsigned)f2bf(a.z) | ((unsigned)f2bf(a.w) << 16));
    r.z = (int)((unsigned)f2bf(b.x) | ((unsigned)f2bf(b.y) << 16));
    r.w = (int)((unsigned)f2bf(b.z) | ((unsigned)f2bf(b.w) << 16));
    return r;
}

// async global->LDS, 16B per lane, LDS dest = wave-uniform base + lane*16
__device__ __forceinline__ void gload_lds16(const u16* g, u16* l) {
    __builtin_amdgcn_global_load_lds(
        (const __attribute__((address_space(1))) void*)g,
        (__attribute__((address_space(3))) void*)l, 16, 0, 0);
}

// ---------------------------------------------------------------------------
// Kernel 0: fp32 -> bf16 convert of x (4M), w_qkv (3M), w_out (1M) into ws.
// ---------------------------------------------------------------------------
__global__ __launch_bounds__(256) void cvt_kernel(
    const float* __restrict__ x, const float* __restrict__ wq,
    const float* __restrict__ wo, u16* __restrict__ outb)
{
    size_t i = ((size_t)blockIdx.x * 256 + threadIdx.x) * 8;
    const float* src;
    size_t off;
    if (i < 4194304)      { src = x;  off = i; }
    else if (i < 7340032) { src = wq; off = i - 4194304; }
    else                  { src = wo; off = i - 7340032; }
    float4 a = *(const float4*)(src + off);
    float4 b = *(const float4*)(src + off + 4);
    *(int4*)(outb + i) = pack8(a, b);
}

// ---------------------------------------------------------------------------
// Kernel 1: QKV projection (bf16 GEMM). C[m,f] = sum_k X[m,k]*Wqkv[f,k]
// M=4096, K=1024, N=3072. 128x128 tile, 4 waves (2x2), K-step 64.
// global_load_lds staging, pre-swizzled source chunks, XOR-swizzled reads.
// Epilogue scatters q (scaled by 0.125*log2e), k, v (transposed [B,H,D,N]).
// ---------------------------------------------------------------------------
__global__ __launch_bounds__(256) void qkv_gemm_kernel(
    const u16* __restrict__ X, const u16* __restrict__ W,
    u16* __restrict__ qws, u16* __restrict__ kws, u16* __restrict__ vws)
{
    __shared__ __align__(16) u16 Ash[128 * 64];
    __shared__ __align__(16) u16 Bsh[128 * 64];
    const int bm = blockIdx.x, bn = blockIdx.y;
    const int tid = threadIdx.x;
    const int lane = tid & 63, wid = tid >> 6;
    const int wm = wid >> 1, wn = wid & 1;
    const int g = lane >> 4, lq = lane & 15;

    f32x4 acc[4][4];
#pragma unroll
    for (int i = 0; i < 4; i++)
#pragma unroll
        for (int j = 0; j < 4; j++) acc[i][j] = (f32x4){0.f, 0.f, 0.f, 0.f};

    const int lrow = lane >> 3;            // 0..7 (row within 8-row sub-block)
    const int lchunk = (lane & 7) ^ lrow;  // pre-swizzled source 16B-chunk
    const u16* Ab = X + (size_t)(bm * 128 + lrow) * 1024 + lchunk * 8;
    const u16* Bb = W + (size_t)(bn * 128 + lrow) * 1024 + lchunk * 8;

    for (int kt = 0; kt < 16; ++kt) {
#pragma unroll
        for (int i = 0; i < 4; i++) {
            int sub = i * 4 + wid;  // wave-uniform 8-row sub-block, 0..15
            gload_lds16(Ab + (size_t)sub * 8192 + kt * 64, &Ash[sub * 512]);
            gload_lds16(Bb + (size_t)sub * 8192 + kt * 64, &Bsh[sub * 512]);
        }
        __syncthreads();
#pragma unroll
        for (int ka = 0; ka < 2; ka++) {
            bf16x8 af[4], bfr[4];
#pragma unroll
            for (int mt = 0; mt < 4; mt++) {
                int row = wm * 64 + mt * 16 + lq;
                af[mt] = *(const bf16x8*)&Ash[row * 64 + (((ka * 4 + g) ^ (row & 7)) << 3)];
            }
#pragma unroll
            for (int nt = 0; nt < 4; nt++) {
                int row = wn * 64 + nt * 16 + lq;
                bfr[nt] = *(const bf16x8*)&Bsh[row * 64 + (((ka * 4 + g) ^ (row & 7)) << 3)];
            }
#pragma unroll
            for (int mt = 0; mt < 4; mt++)
#pragma unroll
                for (int nt = 0; nt < 4; nt++)
                    acc[mt][nt] = MFMA16(af[mt], bfr[nt], acc[mt][nt]);
        }
        __syncthreads();
    }

#pragma unroll
    for (int mt = 0; mt < 4; mt++) {
#pragma unroll
        for (int nt = 0; nt < 4; nt++) {
            int f = bn * 128 + wn * 64 + nt * 16 + lq;
            int t = f >> 10, h = (f >> 6) & 15, d = f & 63;
            int mbase = bm * 128 + wm * 64 + mt * 16 + g * 4;
            int b = mbase >> 11, n0 = mbase & 2047;
            if (t == 0) {
#pragma unroll
                for (int r = 0; r < 4; r++)
                    qws[((size_t)(b * 16 + h) * 2048 + n0 + r) * 64 + d] =
                        f2bf(acc[mt][nt][r] * 0.18033688f);  // 0.125*log2(e)
            } else if (t == 1) {
#pragma unroll
                for (int r = 0; r < 4; r++)
                    kws[((size_t)(b * 16 + h) * 2048 + n0 + r) * 64 + d] =
                        f2bf(acc[mt][nt][r]);
            } else {
                ushort4 pk;
                pk.x = f2bf(acc[mt][nt][0]);
                pk.y = f2bf(acc[mt][nt][1]);
                pk.z = f2bf(acc[mt][nt][2]);
                pk.w = f2bf(acc[mt][nt][3]);
                *(ushort4*)&vws[((size_t)(b * 16 + h) * 64 + d) * 2048 + n0] = pk;
            }
        }
    }
}

// ---------------------------------------------------------------------------
// Kernel 2: flash attention, barrier-free.
// Grid (B*H=32, N/64=32). 4 waves; each wave owns 16 q-rows, free-running.
// K/V fragments read DIRECTLY from global (L1/L2-resident: 512KB per bh,
// all 32 qt-blocks of a bh land on the same XCD since grid stride 32 % 8==0).
// Softmax denominator via ones-B MFMA (row sums in oacc layout).
// P transposed through per-wave LDS (wave-local, lgkmcnt only, no barrier).
// ---------------------------------------------------------------------------
__global__ __launch_bounds__(256) void attn_kernel(
    const u16* __restrict__ qws, const u16* __restrict__ kws,
    const u16* __restrict__ vws, u16* __restrict__ ows)
{
    __shared__ __align__(16) u16 Psh[4][16 * 64];     // per-wave [q][kv]
    const int bh = blockIdx.x, qt = blockIdx.y;
    const int b = bh >> 4, h = bh & 15;
    const int tid = threadIdx.x, wid = tid >> 6, lane = tid & 63;
    const int g = lane >> 4, lq = lane & 15;

    const u16* Qp = qws + ((size_t)bh * 2048 + qt * 64 + wid * 16) * 64;
    // per-lane K row pointer: row = lq (advance by kt*64 rows each iter)
    const u16* Kp = kws + (size_t)bh * 2048 * 64 + (size_t)lq * 64;
    // per-lane V row pointers: row = dt*16 + lq (d-major layout [B,H,D,N])
    const u16* Vp = vws + (size_t)bh * 64 * 2048 + (size_t)lq * 2048;

    bf16x8 qf0 = *(const bf16x8*)(Qp + lq * 64 + g * 8);
    bf16x8 qf1 = *(const bf16x8*)(Qp + lq * 64 + 32 + g * 8);

    // all-ones bf16 B fragment for row-sum MFMA
    bf16x8 onesB;
#pragma unroll
    for (int i = 0; i < 8; i++) onesB[i] = (short)0x3F80;

    f32x4 oacc[4];
#pragma unroll
    for (int i = 0; i < 4; i++) oacc[i] = (f32x4){0.f, 0.f, 0.f, 0.f};
    f32x4 lacc = (f32x4){0.f, 0.f, 0.f, 0.f};

    for (int kt = 0; kt < 32; ++kt) {
        const u16* kRow = Kp + (size_t)kt * 64 * 64;   // K[kt*64 + lq][*]

        // S = Q*K^T  (log2 domain: q pre-scaled by 0.125*log2e)
        f32x4 s[4];
#pragma unroll
        for (int nt = 0; nt < 4; nt++) {
            const u16* kr = kRow + nt * 16 * 64;
            bf16x8 kb0 = *(const bf16x8*)(kr + g * 8);
            bf16x8 kb1 = *(const bf16x8*)(kr + 32 + g * 8);
            f32x4 z = (f32x4){0.f, 0.f, 0.f, 0.f};
            z = MFMA16(qf0, kb0, z);
            z = MFMA16(qf1, kb1, z);
            s[nt] = z;
        }
#pragma unroll
        for (int nt = 0; nt < 4; nt++)
#pragma unroll
            for (int r = 0; r < 4; r++)
                s[nt][r] = __builtin_amdgcn_exp2f(s[nt][r]);

        // store P (bf16) to per-wave LDS: [q=g*4+r][kv=nt*16+lq], chunk-swizzled
#pragma unroll
        for (int nt = 0; nt < 4; nt++)
#pragma unroll
            for (int r = 0; r < 4; r++) {
                int row = g * 4 + r, kv = nt * 16 + lq;
                Psh[wid][row * 64 + ((((kv >> 3) ^ (row & 7)) << 3) | (kv & 7))] = f2bf(s[nt][r]);
            }
        asm volatile("s_waitcnt lgkmcnt(0)" ::: "memory");
        __builtin_amdgcn_sched_barrier(0);

        // P as A-operand: lane holds P[q=lq][kv chunk g], [chunk 4+g]
        bf16x8 pa0 = *(const bf16x8*)&Psh[wid][lq * 64 + ((g ^ (lq & 7)) << 3)];
        bf16x8 pa1 = *(const bf16x8*)&Psh[wid][lq * 64 + (((4 + g) ^ (lq & 7)) << 3)];

        // denominator: rowsum(P) via ones-B MFMA (lands in oacc C-layout)
        lacc = MFMA16(pa0, onesB, lacc);
        lacc = MFMA16(pa1, onesB, lacc);

        // PV: O[q][d] += P[q][kv] * V^T[d][kv]
#pragma unroll
        for (int dt = 0; dt < 4; dt++) {
            const u16* vr = Vp + (size_t)dt * 16 * 2048 + kt * 64;
            bf16x8 vb0 = *(const bf16x8*)(vr + g * 8);
            bf16x8 vb1 = *(const bf16x8*)(vr + 32 + g * 8);
            oacc[dt] = MFMA16(pa0, vb0, oacc[dt]);
            oacc[dt] = MFMA16(pa1, vb1, oacc[dt]);
        }
    }

    // normalize + write O as [B, N, H*D] bf16
#pragma unroll
    for (int dt = 0; dt < 4; dt++)
#pragma unroll
        for (int r = 0; r < 4; r++) {
            int n = qt * 64 + wid * 16 + g * 4 + r;
            ows[((size_t)b * 2048 + n) * 1024 + h * 64 + dt * 16 + lq] =
                f2bf(oacc[dt][r] / lacc[r]);
        }
}

// ---------------------------------------------------------------------------
// Kernel 3: output projection. Out[m,o] = sum_k O[m,k]*Wout[o,k] + bias[o]
// M=4096, N=1024, K=1024. bf16 GEMM, global_load_lds staging, fp32 out.
// ---------------------------------------------------------------------------
__global__ __launch_bounds__(256) void out_gemm_kernel(
    const u16* __restrict__ A, const u16* __restrict__ W,
    const float* __restrict__ bias, float* __restrict__ Out)
{
    __shared__ __align__(16) u16 Ash[128 * 64];
    __shared__ __align__(16) u16 Bsh[128 * 64];
    const int bm = blockIdx.x, bn = blockIdx.y;
    const int tid = threadIdx.x;
    const int lane = tid & 63, wid = tid >> 6;
    const int wm = wid >> 1, wn = wid & 1;
    const int g = lane >> 4, lq = lane & 15;

    f32x4 acc[4][4];
#pragma unroll
    for (int i = 0; i < 4; i++)
#pragma unroll
        for (int j = 0; j < 4; j++) acc[i][j] = (f32x4){0.f, 0.f, 0.f, 0.f};

    const int lrow = lane >> 3;
    const int lchunk = (lane & 7) ^ lrow;
    const u16* Ab = A + (size_t)(bm * 128 + lrow) * 1024 + lchunk * 8;
    const u16* Bb = W + (size_t)(bn * 128 + lrow) * 1024 + lchunk * 8;

    for (int kt = 0; kt < 16; ++kt) {
#pragma unroll
        for (int i = 0; i < 4; i++) {
            int sub = i * 4 + wid;
            gload_lds16(Ab + (size_t)sub * 8192 + kt * 64, &Ash[sub * 512]);
            gload_lds16(Bb + (size_t)sub * 8192 + kt * 64, &Bsh[sub * 512]);
        }
        __syncthreads();
#pragma unroll
        for (int ka = 0; ka < 2; ka++) {
            bf16x8 af[4], bfr[4];
#pragma unroll
            for (int mt = 0; mt < 4; mt++) {
                int row = wm * 64 + mt * 16 + lq;
                af[mt] = *(const bf16x8*)&Ash[row * 64 + (((ka * 4 + g) ^ (row & 7)) << 3)];
            }
#pragma unroll
            for (int nt = 0; nt < 4; nt++) {
                int row = wn * 64 + nt * 16 + lq;
                bfr[nt] = *(const bf16x8*)&Bsh[row * 64 + (((ka * 4 + g) ^ (row & 7)) << 3)];
            }
#pragma unroll
            for (int mt = 0; mt < 4; mt++)
#pragma unroll
                for (int nt = 0; nt < 4; nt++)
                    acc[mt][nt] = MFMA16(af[mt], bfr[nt], acc[mt][nt]);
        }
        __syncthreads();
    }

#pragma unroll
    for (int mt = 0; mt < 4; mt++) {
#pragma unroll
        for (int nt = 0; nt < 4; nt++) {
            int ncol = bn * 128 + wn * 64 + nt * 16 + lq;
            float bv = bias[ncol];
            int mbase = bm * 128 + wm * 64 + mt * 16 + g * 4;
#pragma unroll
            for (int r = 0; r < 4; r++)
                Out[(size_t)(mbase + r) * 1024 + ncol] = acc[mt][nt][r] + bv;
        }
    }
}

extern "C" void kernel_launch(void* const* d_in, const int* in_sizes, int n_in,
                              void* d_out, int out_size, void* d_ws, size_t ws_size,
                              hipStream_t stream) {
    const float* x     = (const float*)d_in[0];  // [2,2048,1024]
    const float* w_qkv = (const float*)d_in[1];  // [3072,1024]
    const float* w_out = (const float*)d_in[2];  // [1024,1024]
    const float* b_out = (const float*)d_in[3];  // [1024]
    float* out = (float*)d_out;                  // [2,2048,1024]

    u16* xb  = (u16*)d_ws;                       // 4M elems
    u16* wqb = xb + 4194304;                     // 3M
    u16* wob = wqb + 3145728;                    // 1M
    u16* qws = wob + 1048576;                    // 4M
    u16* kws = qws + 4194304;                    // 4M
    u16* vws = kws + 4194304;                    // 4M
    u16* ows = vws + 4194304;                    // 4M

    cvt_kernel<<<4096, 256, 0, stream>>>(x, w_qkv, w_out, xb);
    qkv_gemm_kernel<<<dim3(32, 24), 256, 0, stream>>>(xb, wqb, qws, kws, vws);
    attn_kernel<<<dim3(32, 32), 256, 0, stream>>>(qws, kws, vws, ows);
    out_gemm_kernel<<<dim3(32, 8), 256, 0, stream>>>(ows, wob, b_out, out);
}

// Round 4
// 127.500 us; speedup vs baseline: 2.3557x; 2.3557x over previous
//
#include <hip/hip_runtime.h>
#include <hip/hip_bf16.h>

typedef unsigned short u16;
typedef __attribute__((ext_vector_type(4))) float f32x4;
typedef __attribute__((ext_vector_type(8))) short bf16x8;

#define MFMA16(a, b, c) __builtin_amdgcn_mfma_f32_16x16x32_bf16(a, b, c, 0, 0, 0)

// fp32 -> bf16 round-to-nearest-even (finite inputs only)
__device__ __forceinline__ u16 f2bf(float f) {
    union { float f; unsigned u; } v;
    v.f = f;
    unsigned r = v.u + 0x7FFFu + ((v.u >> 16) & 1u);
    return (u16)(r >> 16);
}

__device__ __forceinline__ int4 pack8(const float4 a, const float4 b) {
    int4 r;
    r.x = (int)((unsigned)f2bf(a.x) | ((unsigned)f2bf(a.y) << 16));
    r.y = (int)((unsigned)f2bf(a.z) | ((unsigned)f2bf(a.w) << 16));
    r.z = (int)((unsigned)f2bf(b.x) | ((unsigned)f2bf(b.y) << 16));
    r.w = (int)((unsigned)f2bf(b.z) | ((unsigned)f2bf(b.w) << 16));
    return r;
}

// packed fp32x2 -> bf16x2 (v_cvt_pk_bf16_f32)
__device__ __forceinline__ unsigned pk2(float a, float b) {
    __hip_bfloat162 t = __float22bfloat162_rn(make_float2(a, b));
    union { __hip_bfloat162 h; unsigned u; } c;
    c.h = t;
    return c.u;
}

// async global->LDS, 16B per lane, LDS dest = wave-uniform base + lane*16
__device__ __forceinline__ void gload_lds16(const u16* g, u16* l) {
    __builtin_amdgcn_global_load_lds(
        (const __attribute__((address_space(1))) void*)g,
        (__attribute__((address_space(3))) void*)l, 16, 0, 0);
}

// ---------------------------------------------------------------------------
// Kernel 0: fp32 -> bf16 convert of x (4M), w_qkv (3M), w_out (1M) into ws.
// ---------------------------------------------------------------------------
__global__ __launch_bounds__(256) void cvt_kernel(
    const float* __restrict__ x, const float* __restrict__ wq,
    const float* __restrict__ wo, u16* __restrict__ outb)
{
    size_t i = ((size_t)blockIdx.x * 256 + threadIdx.x) * 8;
    const float* src;
    size_t off;
    if (i < 4194304)      { src = x;  off = i; }
    else if (i < 7340032) { src = wq; off = i - 4194304; }
    else                  { src = wo; off = i - 7340032; }
    float4 a = *(const float4*)(src + off);
    float4 b = *(const float4*)(src + off + 4);
    *(int4*)(outb + i) = pack8(a, b);
}

// ---------------------------------------------------------------------------
// Kernel 1: QKV projection (bf16 GEMM). 128x128 tile, 4 waves, K-step 64.
// global_load_lds staging, pre-swizzled source chunks, XOR-swizzled reads.
// Epilogue scatters q (scaled by 0.125*log2e), k, v (transposed [B,H,D,N]).
// ---------------------------------------------------------------------------
__global__ __launch_bounds__(256) void qkv_gemm_kernel(
    const u16* __restrict__ X, const u16* __restrict__ W,
    u16* __restrict__ qws, u16* __restrict__ kws, u16* __restrict__ vws)
{
    __shared__ __align__(16) u16 Ash[128 * 64];
    __shared__ __align__(16) u16 Bsh[128 * 64];
    const int bm = blockIdx.x, bn = blockIdx.y;
    const int tid = threadIdx.x;
    const int lane = tid & 63, wid = tid >> 6;
    const int wm = wid >> 1, wn = wid & 1;
    const int g = lane >> 4, lq = lane & 15;

    f32x4 acc[4][4];
#pragma unroll
    for (int i = 0; i < 4; i++)
#pragma unroll
        for (int j = 0; j < 4; j++) acc[i][j] = (f32x4){0.f, 0.f, 0.f, 0.f};

    const int lrow = lane >> 3;
    const int lchunk = (lane & 7) ^ lrow;
    const u16* Ab = X + (size_t)(bm * 128 + lrow) * 1024 + lchunk * 8;
    const u16* Bb = W + (size_t)(bn * 128 + lrow) * 1024 + lchunk * 8;

    for (int kt = 0; kt < 16; ++kt) {
#pragma unroll
        for (int i = 0; i < 4; i++) {
            int sub = i * 4 + wid;
            gload_lds16(Ab + (size_t)sub * 8192 + kt * 64, &Ash[sub * 512]);
            gload_lds16(Bb + (size_t)sub * 8192 + kt * 64, &Bsh[sub * 512]);
        }
        __syncthreads();
#pragma unroll
        for (int ka = 0; ka < 2; ka++) {
            bf16x8 af[4], bfr[4];
#pragma unroll
            for (int mt = 0; mt < 4; mt++) {
                int row = wm * 64 + mt * 16 + lq;
                af[mt] = *(const bf16x8*)&Ash[row * 64 + (((ka * 4 + g) ^ (row & 7)) << 3)];
            }
#pragma unroll
            for (int nt = 0; nt < 4; nt++) {
                int row = wn * 64 + nt * 16 + lq;
                bfr[nt] = *(const bf16x8*)&Bsh[row * 64 + (((ka * 4 + g) ^ (row & 7)) << 3)];
            }
#pragma unroll
            for (int mt = 0; mt < 4; mt++)
#pragma unroll
                for (int nt = 0; nt < 4; nt++)
                    acc[mt][nt] = MFMA16(af[mt], bfr[nt], acc[mt][nt]);
        }
        __syncthreads();
    }

#pragma unroll
    for (int mt = 0; mt < 4; mt++) {
#pragma unroll
        for (int nt = 0; nt < 4; nt++) {
            int f = bn * 128 + wn * 64 + nt * 16 + lq;
            int t = f >> 10, h = (f >> 6) & 15, d = f & 63;
            int mbase = bm * 128 + wm * 64 + mt * 16 + g * 4;
            int b = mbase >> 11, n0 = mbase & 2047;
            if (t == 0) {
#pragma unroll
                for (int r = 0; r < 4; r++)
                    qws[((size_t)(b * 16 + h) * 2048 + n0 + r) * 64 + d] =
                        f2bf(acc[mt][nt][r] * 0.18033688f);  // 0.125*log2(e)
            } else if (t == 1) {
#pragma unroll
                for (int r = 0; r < 4; r++)
                    kws[((size_t)(b * 16 + h) * 2048 + n0 + r) * 64 + d] =
                        f2bf(acc[mt][nt][r]);
            } else {
                ushort4 pk;
                pk.x = f2bf(acc[mt][nt][0]);
                pk.y = f2bf(acc[mt][nt][1]);
                pk.z = f2bf(acc[mt][nt][2]);
                pk.w = f2bf(acc[mt][nt][3]);
                *(ushort4*)&vws[((size_t)(b * 16 + h) * 64 + d) * 2048 + n0] = pk;
            }
        }
    }
}

// ---------------------------------------------------------------------------
// Kernel 2: flash attention. Grid (B*H=32, N/128=16). 4 waves x 32 q-rows.
// K/V staged via global_load_lds into double-buffered swizzled LDS,
// counted vmcnt(4) pipeline (stage kt+1 while computing kt).
// Swapped QK^T (MFMA(K,Q)) puts P at 4 consecutive kv per lane ->
// packed ds_write_b64 P-transpose through per-wave LDS.
// Softmax denominator via ones-B MFMA (layout-aligned with oacc).
// ---------------------------------------------------------------------------
__global__ __launch_bounds__(256) void attn_kernel(
    const u16* __restrict__ qws, const u16* __restrict__ kws,
    const u16* __restrict__ vws, u16* __restrict__ ows)
{
    __shared__ __align__(16) u16 Ksh[2][64 * 64];   // [kv][d], chunk-swizzled
    __shared__ __align__(16) u16 Vsh[2][64 * 64];   // [d][kv], chunk-swizzled
    __shared__ __align__(16) u16 Psh[4][32 * 64];   // per-wave [q][kv], swizzled
    const int bh = blockIdx.x, qt = blockIdx.y;
    const int b = bh >> 4, h = bh & 15;
    const int tid = threadIdx.x, wid = tid >> 6, lane = tid & 63;
    const int g = lane >> 4, lq = lane & 15;

    const u16* Qp = qws + ((size_t)bh * 2048 + qt * 128 + wid * 32) * 64;
    bf16x8 qf[2][2];
#pragma unroll
    for (int qa = 0; qa < 2; qa++) {
        qf[qa][0] = *(const bf16x8*)(Qp + (qa * 16 + lq) * 64 + g * 8);
        qf[qa][1] = *(const bf16x8*)(Qp + (qa * 16 + lq) * 64 + 32 + g * 8);
    }

    // staging pointers (pre-swizzled 16B source chunks)
    const int lrow = lane >> 3;            // 0..7
    const int lchunk = (lane & 7) ^ lrow;  // XOR pre-swizzle
    const u16* Kb = kws + (size_t)bh * 2048 * 64 + (size_t)lrow * 64 + lchunk * 8;
    const u16* Vb = vws + (size_t)bh * 64 * 2048 + (size_t)lrow * 2048 + lchunk * 8;

#define STAGE(KT, BUF)                                                        \
    {                                                                         \
        _Pragma("unroll")                                                     \
        for (int i = 0; i < 2; i++) {                                         \
            int sub = wid * 2 + i;                                            \
            gload_lds16(Kb + (size_t)((KT) * 64 + sub * 8) * 64,              \
                        &Ksh[BUF][sub * 512]);                                \
            gload_lds16(Vb + (size_t)(sub * 8) * 2048 + (KT) * 64,            \
                        &Vsh[BUF][sub * 512]);                                \
        }                                                                     \
    }

    bf16x8 onesB;
#pragma unroll
    for (int i = 0; i < 8; i++) onesB[i] = (short)0x3F80;

    f32x4 oacc[2][4];
#pragma unroll
    for (int qa = 0; qa < 2; qa++)
#pragma unroll
        for (int i = 0; i < 4; i++) oacc[qa][i] = (f32x4){0.f, 0.f, 0.f, 0.f};
    f32x4 lacc[2] = {(f32x4){0.f, 0.f, 0.f, 0.f}, (f32x4){0.f, 0.f, 0.f, 0.f}};

    STAGE(0, 0);

    for (int kt = 0; kt < 32; ++kt) {
        const int buf = kt & 1;
        STAGE((kt + 1) & 31, buf ^ 1);                 // prefetch next tile
        asm volatile("s_waitcnt vmcnt(4)" ::: "memory");  // this tile's 4 done
        __builtin_amdgcn_s_barrier();
        __builtin_amdgcn_sched_barrier(0);

        // S^T = MFMA(K, Q): lane holds S[q=lq][kv = nt*16 + g*4 + r]
#pragma unroll
        for (int qa = 0; qa < 2; qa++) {
            f32x4 s[4];
#pragma unroll
            for (int nt = 0; nt < 4; nt++) {
                int row = nt * 16 + lq;
                bf16x8 kb0 = *(const bf16x8*)&Ksh[buf][row * 64 + ((g ^ (row & 7)) << 3)];
                bf16x8 kb1 = *(const bf16x8*)&Ksh[buf][row * 64 + (((4 + g) ^ (row & 7)) << 3)];
                f32x4 z = (f32x4){0.f, 0.f, 0.f, 0.f};
                z = MFMA16(kb0, qf[qa][0], z);
                z = MFMA16(kb1, qf[qa][1], z);
                s[nt] = z;
            }
            // p = exp2(s); pack 4 consecutive kv -> one b64 LDS write
            int prow = qa * 16 + lq;
#pragma unroll
            for (int nt = 0; nt < 4; nt++) {
#pragma unroll
                for (int r = 0; r < 4; r++) s[nt][r] = __builtin_amdgcn_exp2f(s[nt][r]);
                uint2 pk;
                pk.x = pk2(s[nt][0], s[nt][1]);
                pk.y = pk2(s[nt][2], s[nt][3]);
                int c16 = nt * 2 + (g >> 1);           // 16B chunk of kv
                *(uint2*)&Psh[wid][prow * 64 + (((c16 ^ (lq & 7)) << 3) | ((g & 1) << 2))] = pk;
            }
        }
        asm volatile("s_waitcnt lgkmcnt(0)" ::: "memory");
        __builtin_amdgcn_sched_barrier(0);

        // PV + rowsum: P as A-operand (row q=lq), V^T as B-operand
#pragma unroll
        for (int qa = 0; qa < 2; qa++) {
            int prow = qa * 16 + lq;
            bf16x8 pa0 = *(const bf16x8*)&Psh[wid][prow * 64 + ((g ^ (lq & 7)) << 3)];
            bf16x8 pa1 = *(const bf16x8*)&Psh[wid][prow * 64 + (((4 + g) ^ (lq & 7)) << 3)];
            lacc[qa] = MFMA16(pa0, onesB, lacc[qa]);
            lacc[qa] = MFMA16(pa1, onesB, lacc[qa]);
#pragma unroll
            for (int dt = 0; dt < 4; dt++) {
                int vrow = dt * 16 + lq;
                bf16x8 vb0 = *(const bf16x8*)&Vsh[buf][vrow * 64 + ((g ^ (vrow & 7)) << 3)];
                bf16x8 vb1 = *(const bf16x8*)&Vsh[buf][vrow * 64 + (((4 + g) ^ (vrow & 7)) << 3)];
                oacc[qa][dt] = MFMA16(pa0, vb0, oacc[qa][dt]);
                oacc[qa][dt] = MFMA16(pa1, vb1, oacc[qa][dt]);
            }
        }
        asm volatile("s_waitcnt lgkmcnt(0)" ::: "memory");  // reads landed
        __builtin_amdgcn_s_barrier();                       // before overwrite
    }
#undef STAGE

    // normalize + write O as [B, N, H*D] bf16
#pragma unroll
    for (int qa = 0; qa < 2; qa++)
#pragma unroll
        for (int dt = 0; dt < 4; dt++)
#pragma unroll
            for (int r = 0; r < 4; r++) {
                int n = qt * 128 + wid * 32 + qa * 16 + g * 4 + r;
                ows[((size_t)b * 2048 + n) * 1024 + h * 64 + dt * 16 + lq] =
                    f2bf(oacc[qa][dt][r] / lacc[qa][r]);
            }
}

// ---------------------------------------------------------------------------
// Kernel 3: output projection. bf16 GEMM, global_load_lds staging, fp32 out.
// ---------------------------------------------------------------------------
__global__ __launch_bounds__(256) void out_gemm_kernel(
    const u16* __restrict__ A, const u16* __restrict__ W,
    const float* __restrict__ bias, float* __restrict__ Out)
{
    __shared__ __align__(16) u16 Ash[128 * 64];
    __shared__ __align__(16) u16 Bsh[128 * 64];
    const int bm = blockIdx.x, bn = blockIdx.y;
    const int tid = threadIdx.x;
    const int lane = tid & 63, wid = tid >> 6;
    const int wm = wid >> 1, wn = wid & 1;
    const int g = lane >> 4, lq = lane & 15;

    f32x4 acc[4][4];
#pragma unroll
    for (int i = 0; i < 4; i++)
#pragma unroll
        for (int j = 0; j < 4; j++) acc[i][j] = (f32x4){0.f, 0.f, 0.f, 0.f};

    const int lrow = lane >> 3;
    const int lchunk = (lane & 7) ^ lrow;
    const u16* Ab = A + (size_t)(bm * 128 + lrow) * 1024 + lchunk * 8;
    const u16* Bb = W + (size_t)(bn * 128 + lrow) * 1024 + lchunk * 8;

    for (int kt = 0; kt < 16; ++kt) {
#pragma unroll
        for (int i = 0; i < 4; i++) {
            int sub = i * 4 + wid;
            gload_lds16(Ab + (size_t)sub * 8192 + kt * 64, &Ash[sub * 512]);
            gload_lds16(Bb + (size_t)sub * 8192 + kt * 64, &Bsh[sub * 512]);
        }
        __syncthreads();
#pragma unroll
        for (int ka = 0; ka < 2; ka++) {
            bf16x8 af[4], bfr[4];
#pragma unroll
            for (int mt = 0; mt < 4; mt++) {
                int row = wm * 64 + mt * 16 + lq;
                af[mt] = *(const bf16x8*)&Ash[row * 64 + (((ka * 4 + g) ^ (row & 7)) << 3)];
            }
#pragma unroll
            for (int nt = 0; nt < 4; nt++) {
                int row = wn * 64 + nt * 16 + lq;
                bfr[nt] = *(const bf16x8*)&Bsh[row * 64 + (((ka * 4 + g) ^ (row & 7)) << 3)];
            }
#pragma unroll
            for (int mt = 0; mt < 4; mt++)
#pragma unroll
                for (int nt = 0; nt < 4; nt++)
                    acc[mt][nt] = MFMA16(af[mt], bfr[nt], acc[mt][nt]);
        }
        __syncthreads();
    }

#pragma unroll
    for (int mt = 0; mt < 4; mt++) {
#pragma unroll
        for (int nt = 0; nt < 4; nt++) {
            int ncol = bn * 128 + wn * 64 + nt * 16 + lq;
            float bv = bias[ncol];
            int mbase = bm * 128 + wm * 64 + mt * 16 + g * 4;
#pragma unroll
            for (int r = 0; r < 4; r++)
                Out[(size_t)(mbase + r) * 1024 + ncol] = acc[mt][nt][r] + bv;
        }
    }
}

extern "C" void kernel_launch(void* const* d_in, const int* in_sizes, int n_in,
                              void* d_out, int out_size, void* d_ws, size_t ws_size,
                              hipStream_t stream) {
    const float* x     = (const float*)d_in[0];  // [2,2048,1024]
    const float* w_qkv = (const float*)d_in[1];  // [3072,1024]
    const float* w_out = (const float*)d_in[2];  // [1024,1024]
    const float* b_out = (const float*)d_in[3];  // [1024]
    float* out = (float*)d_out;                  // [2,2048,1024]

    u16* xb  = (u16*)d_ws;                       // 4M elems
    u16* wqb = xb + 4194304;                     // 3M
    u16* wob = wqb + 3145728;                    // 1M
    u16* qws = wob + 1048576;                    // 4M
    u16* kws = qws + 4194304;                    // 4M
    u16* vws = kws + 4194304;                    // 4M
    u16* ows = vws + 4194304;                    // 4M

    cvt_kernel<<<4096, 256, 0, stream>>>(x, w_qkv, w_out, xb);
    qkv_gemm_kernel<<<dim3(32, 24), 256, 0, stream>>>(xb, wqb, qws, kws, vws);
    attn_kernel<<<dim3(32, 16), 256, 0, stream>>>(qws, kws, vws, ows);
    out_gemm_kernel<<<dim3(32, 8), 256, 0, stream>>>(ows, wob, b_out, out);
}

// Round 5
// 125.701 us; speedup vs baseline: 2.3894x; 1.0143x over previous
//
#include <hip/hip_runtime.h>
#include <hip/hip_bf16.h>

typedef unsigned short u16;
typedef __attribute__((ext_vector_type(4))) float f32x4;
typedef __attribute__((ext_vector_type(8))) short bf16x8;

#define MFMA16(a, b, c) __builtin_amdgcn_mfma_f32_16x16x32_bf16(a, b, c, 0, 0, 0)

// fp32 -> bf16 round-to-nearest-even (finite inputs only)
__device__ __forceinline__ u16 f2bf(float f) {
    union { float f; unsigned u; } v;
    v.f = f;
    unsigned r = v.u + 0x7FFFu + ((v.u >> 16) & 1u);
    return (u16)(r >> 16);
}

__device__ __forceinline__ int4 pack8(const float4 a, const float4 b) {
    int4 r;
    r.x = (int)((unsigned)f2bf(a.x) | ((unsigned)f2bf(a.y) << 16));
    r.y = (int)((unsigned)f2bf(a.z) | ((unsigned)f2bf(a.w) << 16));
    r.z = (int)((unsigned)f2bf(b.x) | ((unsigned)f2bf(b.y) << 16));
    r.w = (int)((unsigned)f2bf(b.z) | ((unsigned)f2bf(b.w) << 16));
    return r;
}

// packed fp32x2 -> bf16x2
__device__ __forceinline__ unsigned pk2(float a, float b) {
    __hip_bfloat162 t = __float22bfloat162_rn(make_float2(a, b));
    union { __hip_bfloat162 h; unsigned u; } c;
    c.h = t;
    return c.u;
}

// async global->LDS, 16B per lane, LDS dest = wave-uniform base + lane*16
__device__ __forceinline__ void gload_lds16(const u16* g, u16* l) {
    __builtin_amdgcn_global_load_lds(
        (const __attribute__((address_space(1))) void*)g,
        (__attribute__((address_space(3))) void*)l, 16, 0, 0);
}

// ---------------------------------------------------------------------------
// Kernel 0: fp32 -> bf16 convert of x (4M), w_qkv (3M), w_out (1M) into ws.
// ---------------------------------------------------------------------------
__global__ __launch_bounds__(256) void cvt_kernel(
    const float* __restrict__ x, const float* __restrict__ wq,
    const float* __restrict__ wo, u16* __restrict__ outb)
{
    size_t i = ((size_t)blockIdx.x * 256 + threadIdx.x) * 8;
    const float* src;
    size_t off;
    if (i < 4194304)      { src = x;  off = i; }
    else if (i < 7340032) { src = wq; off = i - 4194304; }
    else                  { src = wo; off = i - 7340032; }
    float4 a = *(const float4*)(src + off);
    float4 b = *(const float4*)(src + off + 4);
    *(int4*)(outb + i) = pack8(a, b);
}

// ---------------------------------------------------------------------------
// Kernel 1: QKV projection (bf16 GEMM). 128x128 tile, 4 waves, K-step 64.
// Epilogue scatters q (scaled by 0.125*log2e), k, v (transposed [B,H,D,N]).
// ---------------------------------------------------------------------------
__global__ __launch_bounds__(256) void qkv_gemm_kernel(
    const u16* __restrict__ X, const u16* __restrict__ W,
    u16* __restrict__ qws, u16* __restrict__ kws, u16* __restrict__ vws)
{
    __shared__ __align__(16) u16 Ash[128 * 64];
    __shared__ __align__(16) u16 Bsh[128 * 64];
    const int bm = blockIdx.x, bn = blockIdx.y;
    const int tid = threadIdx.x;
    const int lane = tid & 63, wid = tid >> 6;
    const int wm = wid >> 1, wn = wid & 1;
    const int g = lane >> 4, lq = lane & 15;

    f32x4 acc[4][4];
#pragma unroll
    for (int i = 0; i < 4; i++)
#pragma unroll
        for (int j = 0; j < 4; j++) acc[i][j] = (f32x4){0.f, 0.f, 0.f, 0.f};

    const int lrow = lane >> 3;
    const int lchunk = (lane & 7) ^ lrow;
    const u16* Ab = X + (size_t)(bm * 128 + lrow) * 1024 + lchunk * 8;
    const u16* Bb = W + (size_t)(bn * 128 + lrow) * 1024 + lchunk * 8;

    for (int kt = 0; kt < 16; ++kt) {
#pragma unroll
        for (int i = 0; i < 4; i++) {
            int sub = i * 4 + wid;
            gload_lds16(Ab + (size_t)sub * 8192 + kt * 64, &Ash[sub * 512]);
            gload_lds16(Bb + (size_t)sub * 8192 + kt * 64, &Bsh[sub * 512]);
        }
        __syncthreads();
#pragma unroll
        for (int ka = 0; ka < 2; ka++) {
            bf16x8 af[4], bfr[4];
#pragma unroll
            for (int mt = 0; mt < 4; mt++) {
                int row = wm * 64 + mt * 16 + lq;
                af[mt] = *(const bf16x8*)&Ash[row * 64 + (((ka * 4 + g) ^ (row & 7)) << 3)];
            }
#pragma unroll
            for (int nt = 0; nt < 4; nt++) {
                int row = wn * 64 + nt * 16 + lq;
                bfr[nt] = *(const bf16x8*)&Bsh[row * 64 + (((ka * 4 + g) ^ (row & 7)) << 3)];
            }
#pragma unroll
            for (int mt = 0; mt < 4; mt++)
#pragma unroll
                for (int nt = 0; nt < 4; nt++)
                    acc[mt][nt] = MFMA16(af[mt], bfr[nt], acc[mt][nt]);
        }
        __syncthreads();
    }

#pragma unroll
    for (int mt = 0; mt < 4; mt++) {
#pragma unroll
        for (int nt = 0; nt < 4; nt++) {
            int f = bn * 128 + wn * 64 + nt * 16 + lq;
            int t = f >> 10, h = (f >> 6) & 15, d = f & 63;
            int mbase = bm * 128 + wm * 64 + mt * 16 + g * 4;
            int b = mbase >> 11, n0 = mbase & 2047;
            if (t == 0) {
#pragma unroll
                for (int r = 0; r < 4; r++)
                    qws[((size_t)(b * 16 + h) * 2048 + n0 + r) * 64 + d] =
                        f2bf(acc[mt][nt][r] * 0.18033688f);  // 0.125*log2(e)
            } else if (t == 1) {
#pragma unroll
                for (int r = 0; r < 4; r++)
                    kws[((size_t)(b * 16 + h) * 2048 + n0 + r) * 64 + d] =
                        f2bf(acc[mt][nt][r]);
            } else {
                ushort4 pk;
                pk.x = f2bf(acc[mt][nt][0]);
                pk.y = f2bf(acc[mt][nt][1]);
                pk.z = f2bf(acc[mt][nt][2]);
                pk.w = f2bf(acc[mt][nt][3]);
                *(ushort4*)&vws[((size_t)(b * 16 + h) * 64 + d) * 2048 + n0] = pk;
            }
        }
    }
}

// ---------------------------------------------------------------------------
// Kernel 2: flash attention, KV-split 2. Grid (32 bh, 8 qt, 2 kvh).
// 4 waves x 64 q-rows; 16 KV-tiles of 64. Double-buffered gload_lds staging,
// counted vmcnt(4). Swapped QK^T -> packed b64 P-transpose via per-wave LDS.
// Unnormalized fp32 partials + l-sums to ws (no-max softmax => plain sums).
// ---------------------------------------------------------------------------
__global__ __launch_bounds__(256, 2) void attn_kernel(
    const u16* __restrict__ qws, const u16* __restrict__ kws,
    const u16* __restrict__ vws, float* __restrict__ Opart,
    float* __restrict__ lpart)
{
    __shared__ __align__(16) u16 Ksh[2][64 * 64];   // [kv][d], chunk-swizzled
    __shared__ __align__(16) u16 Vsh[2][64 * 64];   // [d][kv], chunk-swizzled
    __shared__ __align__(16) u16 Psh[4][64 * 64];   // per-wave [q][kv], swizzled
    const int bh = blockIdx.x, qt = blockIdx.y, kvh = blockIdx.z;
    const int tid = threadIdx.x, wid = tid >> 6, lane = tid & 63;
    const int g = lane >> 4, lq = lane & 15;

    const u16* Qp = qws + ((size_t)bh * 2048 + qt * 256 + wid * 64) * 64;
    bf16x8 qf[4][2];
#pragma unroll
    for (int qa = 0; qa < 4; qa++) {
        qf[qa][0] = *(const bf16x8*)(Qp + (qa * 16 + lq) * 64 + g * 8);
        qf[qa][1] = *(const bf16x8*)(Qp + (qa * 16 + lq) * 64 + 32 + g * 8);
    }

    const int lrow = lane >> 3;            // 0..7
    const int lchunk = (lane & 7) ^ lrow;  // XOR pre-swizzle
    const u16* Kb = kws + (size_t)bh * 2048 * 64 + (size_t)lrow * 64 + lchunk * 8;
    const u16* Vb = vws + (size_t)bh * 64 * 2048 + (size_t)lrow * 2048 + lchunk * 8;

#define STAGE(TG, BUF)                                                        \
    {                                                                         \
        _Pragma("unroll")                                                     \
        for (int i = 0; i < 2; i++) {                                         \
            int sub = wid * 2 + i;                                            \
            gload_lds16(Kb + (size_t)((TG) * 64 + sub * 8) * 64,              \
                        &Ksh[BUF][sub * 512]);                                \
            gload_lds16(Vb + (size_t)(sub * 8) * 2048 + (TG) * 64,            \
                        &Vsh[BUF][sub * 512]);                                \
        }                                                                     \
    }

    bf16x8 onesB;
#pragma unroll
    for (int i = 0; i < 8; i++) onesB[i] = (short)0x3F80;

    f32x4 oacc[4][4];
#pragma unroll
    for (int qa = 0; qa < 4; qa++)
#pragma unroll
        for (int i = 0; i < 4; i++) oacc[qa][i] = (f32x4){0.f, 0.f, 0.f, 0.f};
    f32x4 lacc[4];
#pragma unroll
    for (int qa = 0; qa < 4; qa++) lacc[qa] = (f32x4){0.f, 0.f, 0.f, 0.f};

    const int tbase = kvh * 16;
    STAGE(tbase, 0);

    for (int t = 0; t < 16; ++t) {
        const int buf = t & 1;
        STAGE(tbase + ((t + 1) & 15), buf ^ 1);           // prefetch next tile
        asm volatile("s_waitcnt vmcnt(4)" ::: "memory");  // this tile's 4 done
        __builtin_amdgcn_s_barrier();
        __builtin_amdgcn_sched_barrier(0);

        // QK^T (swapped): per nt load K-frags once, reuse across 4 q-subtiles
#pragma unroll
        for (int nt = 0; nt < 4; nt++) {
            int row = nt * 16 + lq;
            bf16x8 kb0 = *(const bf16x8*)&Ksh[buf][row * 64 + ((g ^ (row & 7)) << 3)];
            bf16x8 kb1 = *(const bf16x8*)&Ksh[buf][row * 64 + (((4 + g) ^ (row & 7)) << 3)];
            int c16 = nt * 2 + (g >> 1);
#pragma unroll
            for (int qa = 0; qa < 4; qa++) {
                f32x4 z = (f32x4){0.f, 0.f, 0.f, 0.f};
                z = MFMA16(kb0, qf[qa][0], z);
                z = MFMA16(kb1, qf[qa][1], z);
#pragma unroll
                for (int r = 0; r < 4; r++) z[r] = __builtin_amdgcn_exp2f(z[r]);
                uint2 pk;
                pk.x = pk2(z[0], z[1]);
                pk.y = pk2(z[2], z[3]);
                int prow = qa * 16 + lq;
                *(uint2*)&Psh[wid][prow * 64 + (((c16 ^ (lq & 7)) << 3) | ((g & 1) << 2))] = pk;
            }
        }
        asm volatile("s_waitcnt lgkmcnt(0)" ::: "memory");
        __builtin_amdgcn_sched_barrier(0);

        // PV + rowsum, in q-subtile pairs (bounds VGPR)
        __builtin_amdgcn_s_setprio(1);
#pragma unroll
        for (int qp = 0; qp < 2; qp++) {
            bf16x8 pa[2][2];
#pragma unroll
            for (int q2 = 0; q2 < 2; q2++) {
                int prow = (qp * 2 + q2) * 16 + lq;
                pa[q2][0] = *(const bf16x8*)&Psh[wid][prow * 64 + ((g ^ (lq & 7)) << 3)];
                pa[q2][1] = *(const bf16x8*)&Psh[wid][prow * 64 + (((4 + g) ^ (lq & 7)) << 3)];
                lacc[qp * 2 + q2] = MFMA16(pa[q2][0], onesB, lacc[qp * 2 + q2]);
                lacc[qp * 2 + q2] = MFMA16(pa[q2][1], onesB, lacc[qp * 2 + q2]);
            }
#pragma unroll
            for (int dt = 0; dt < 4; dt++) {
                int vrow = dt * 16 + lq;
                bf16x8 vb0 = *(const bf16x8*)&Vsh[buf][vrow * 64 + ((g ^ (vrow & 7)) << 3)];
                bf16x8 vb1 = *(const bf16x8*)&Vsh[buf][vrow * 64 + (((4 + g) ^ (vrow & 7)) << 3)];
#pragma unroll
                for (int q2 = 0; q2 < 2; q2++) {
                    oacc[qp * 2 + q2][dt] = MFMA16(pa[q2][0], vb0, oacc[qp * 2 + q2][dt]);
                    oacc[qp * 2 + q2][dt] = MFMA16(pa[q2][1], vb1, oacc[qp * 2 + q2][dt]);
                }
            }
        }
        __builtin_amdgcn_s_setprio(0);
        asm volatile("s_waitcnt lgkmcnt(0)" ::: "memory");  // reads landed
        __builtin_amdgcn_s_barrier();                       // before overwrite
    }
#undef STAGE

    // unnormalized fp32 partials
    const int nbase = qt * 256 + wid * 64;
#pragma unroll
    for (int qa = 0; qa < 4; qa++) {
#pragma unroll
        for (int dt = 0; dt < 4; dt++)
#pragma unroll
            for (int r = 0; r < 4; r++) {
                int n = nbase + qa * 16 + g * 4 + r;
                Opart[(size_t)kvh * 4194304 + ((size_t)bh * 2048 + n) * 64 + dt * 16 + lq] =
                    oacc[qa][dt][r];
            }
        if (lq == 0) {
#pragma unroll
            for (int r = 0; r < 4; r++)
                lpart[kvh * 65536 + bh * 2048 + nbase + qa * 16 + g * 4 + r] =
                    lacc[qa][r];
        }
    }
}

// ---------------------------------------------------------------------------
// Kernel 2b: combine the two KV-half partials: O = (O0+O1)/(l0+l1) -> bf16.
// Writes ows as [B, N, H*D]. 1M threads x 4 elems.
// ---------------------------------------------------------------------------
__global__ __launch_bounds__(256) void combine_kernel(
    const float* __restrict__ Opart, const float* __restrict__ lpart,
    u16* __restrict__ ows)
{
    int idx = blockIdx.x * 256 + threadIdx.x;
    int d4 = (idx & 15) * 4;
    int n  = (idx >> 4) & 2047;
    int bh = idx >> 15;
    size_t o = ((size_t)bh * 2048 + n) * 64 + d4;
    float4 a = *(const float4*)(Opart + o);
    float4 c = *(const float4*)(Opart + 4194304 + o);
    float rl = 1.0f / (lpart[bh * 2048 + n] + lpart[65536 + bh * 2048 + n]);
    ushort4 pk;
    pk.x = f2bf((a.x + c.x) * rl);
    pk.y = f2bf((a.y + c.y) * rl);
    pk.z = f2bf((a.z + c.z) * rl);
    pk.w = f2bf((a.w + c.w) * rl);
    int b = bh >> 4, h = bh & 15;
    *(ushort4*)&ows[((size_t)b * 2048 + n) * 1024 + h * 64 + d4] = pk;
}

// ---------------------------------------------------------------------------
// Kernel 3: output projection. bf16 GEMM, global_load_lds staging, fp32 out.
// ---------------------------------------------------------------------------
__global__ __launch_bounds__(256) void out_gemm_kernel(
    const u16* __restrict__ A, const u16* __restrict__ W,
    const float* __restrict__ bias, float* __restrict__ Out)
{
    __shared__ __align__(16) u16 Ash[128 * 64];
    __shared__ __align__(16) u16 Bsh[128 * 64];
    const int bm = blockIdx.x, bn = blockIdx.y;
    const int tid = threadIdx.x;
    const int lane = tid & 63, wid = tid >> 6;
    const int wm = wid >> 1, wn = wid & 1;
    const int g = lane >> 4, lq = lane & 15;

    f32x4 acc[4][4];
#pragma unroll
    for (int i = 0; i < 4; i++)
#pragma unroll
        for (int j = 0; j < 4; j++) acc[i][j] = (f32x4){0.f, 0.f, 0.f, 0.f};

    const int lrow = lane >> 3;
    const int lchunk = (lane & 7) ^ lrow;
    const u16* Ab = A + (size_t)(bm * 128 + lrow) * 1024 + lchunk * 8;
    const u16* Bb = W + (size_t)(bn * 128 + lrow) * 1024 + lchunk * 8;

    for (int kt = 0; kt < 16; ++kt) {
#pragma unroll
        for (int i = 0; i < 4; i++) {
            int sub = i * 4 + wid;
            gload_lds16(Ab + (size_t)sub * 8192 + kt * 64, &Ash[sub * 512]);
            gload_lds16(Bb + (size_t)sub * 8192 + kt * 64, &Bsh[sub * 512]);
        }
        __syncthreads();
#pragma unroll
        for (int ka = 0; ka < 2; ka++) {
            bf16x8 af[4], bfr[4];
#pragma unroll
            for (int mt = 0; mt < 4; mt++) {
                int row = wm * 64 + mt * 16 + lq;
                af[mt] = *(const bf16x8*)&Ash[row * 64 + (((ka * 4 + g) ^ (row & 7)) << 3)];
            }
#pragma unroll
            for (int nt = 0; nt < 4; nt++) {
                int row = wn * 64 + nt * 16 + lq;
                bfr[nt] = *(const bf16x8*)&Bsh[row * 64 + (((ka * 4 + g) ^ (row & 7)) << 3)];
            }
#pragma unroll
            for (int mt = 0; mt < 4; mt++)
#pragma unroll
                for (int nt = 0; nt < 4; nt++)
                    acc[mt][nt] = MFMA16(af[mt], bfr[nt], acc[mt][nt]);
        }
        __syncthreads();
    }

#pragma unroll
    for (int mt = 0; mt < 4; mt++) {
#pragma unroll
        for (int nt = 0; nt < 4; nt++) {
            int ncol = bn * 128 + wn * 64 + nt * 16 + lq;
            float bv = bias[ncol];
            int mbase = bm * 128 + wm * 64 + mt * 16 + g * 4;
#pragma unroll
            for (int r = 0; r < 4; r++)
                Out[(size_t)(mbase + r) * 1024 + ncol] = acc[mt][nt][r] + bv;
        }
    }
}

extern "C" void kernel_launch(void* const* d_in, const int* in_sizes, int n_in,
                              void* d_out, int out_size, void* d_ws, size_t ws_size,
                              hipStream_t stream) {
    const float* x     = (const float*)d_in[0];  // [2,2048,1024]
    const float* w_qkv = (const float*)d_in[1];  // [3072,1024]
    const float* w_out = (const float*)d_in[2];  // [1024,1024]
    const float* b_out = (const float*)d_in[3];  // [1024]
    float* out = (float*)d_out;                  // [2,2048,1024]

    u16* xb  = (u16*)d_ws;                       // 4M elems
    u16* wqb = xb + 4194304;                     // 3M
    u16* wob = wqb + 3145728;                    // 1M
    u16* qws = wob + 1048576;                    // 4M
    u16* kws = qws + 4194304;                    // 4M
    u16* vws = kws + 4194304;                    // 4M
    u16* ows = vws + 4194304;                    // 4M
    float* Opart = (float*)(ows + 4194304);      // 8M floats (2 x 4M)
    float* lpart = Opart + 8388608;              // 128K floats

    cvt_kernel<<<4096, 256, 0, stream>>>(x, w_qkv, w_out, xb);
    qkv_gemm_kernel<<<dim3(32, 24), 256, 0, stream>>>(xb, wqb, qws, kws, vws);
    attn_kernel<<<dim3(32, 8, 2), 256, 0, stream>>>(qws, kws, vws, Opart, lpart);
    combine_kernel<<<4096, 256, 0, stream>>>(Opart, lpart, ows);
    out_gemm_kernel<<<dim3(32, 8), 256, 0, stream>>>(ows, wob, b_out, out);
}

// Round 6
// 113.639 us; speedup vs baseline: 2.6430x; 1.1061x over previous
//
#include <hip/hip_runtime.h>
#include <hip/hip_bf16.h>

typedef unsigned short u16;
typedef __attribute__((ext_vector_type(4))) float f32x4;
typedef __attribute__((ext_vector_type(8))) short bf16x8;

#define MFMA16(a, b, c) __builtin_amdgcn_mfma_f32_16x16x32_bf16(a, b, c, 0, 0, 0)

// fp32 -> bf16 round-to-nearest-even (finite inputs only)
__device__ __forceinline__ u16 f2bf(float f) {
    union { float f; unsigned u; } v;
    v.f = f;
    unsigned r = v.u + 0x7FFFu + ((v.u >> 16) & 1u);
    return (u16)(r >> 16);
}

__device__ __forceinline__ int4 pack8(const float4 a, const float4 b) {
    int4 r;
    r.x = (int)((unsigned)f2bf(a.x) | ((unsigned)f2bf(a.y) << 16));
    r.y = (int)((unsigned)f2bf(a.z) | ((unsigned)f2bf(a.w) << 16));
    r.z = (int)((unsigned)f2bf(b.x) | ((unsigned)f2bf(b.y) << 16));
    r.w = (int)((unsigned)f2bf(b.z) | ((unsigned)f2bf(b.w) << 16));
    return r;
}

// packed fp32x2 -> bf16x2
__device__ __forceinline__ unsigned pk2(float a, float b) {
    __hip_bfloat162 t = __float22bfloat162_rn(make_float2(a, b));
    union { __hip_bfloat162 h; unsigned u; } c;
    c.h = t;
    return c.u;
}

// async global->LDS, 16B per lane, LDS dest = wave-uniform base + lane*16
__device__ __forceinline__ void gload_lds16(const u16* g, u16* l) {
    __builtin_amdgcn_global_load_lds(
        (const __attribute__((address_space(1))) void*)g,
        (__attribute__((address_space(3))) void*)l, 16, 0, 0);
}

// ---------------------------------------------------------------------------
// Kernel 0: fp32 -> bf16 convert of x (4M), w_qkv (3M), w_out (1M) into ws.
// ---------------------------------------------------------------------------
__global__ __launch_bounds__(256) void cvt_kernel(
    const float* __restrict__ x, const float* __restrict__ wq,
    const float* __restrict__ wo, u16* __restrict__ outb)
{
    size_t i = ((size_t)blockIdx.x * 256 + threadIdx.x) * 8;
    const float* src;
    size_t off;
    if (i < 4194304)      { src = x;  off = i; }
    else if (i < 7340032) { src = wq; off = i - 4194304; }
    else                  { src = wo; off = i - 7340032; }
    float4 a = *(const float4*)(src + off);
    float4 b = *(const float4*)(src + off + 4);
    *(int4*)(outb + i) = pack8(a, b);
}

// ---------------------------------------------------------------------------
// Kernel 1: QKV projection (bf16 GEMM). 256x128 tile, 8 waves (4x2), BK=64.
// Grid: 384 blocks 1-D, XCD-swizzled into 4bm x 12bn L2 regions.
// Epilogue scatters q (scaled by 0.125*log2e), k, v (transposed [B,H,D,N]).
// ---------------------------------------------------------------------------
__global__ __launch_bounds__(512) void qkv_gemm_kernel(
    const u16* __restrict__ X, const u16* __restrict__ W,
    u16* __restrict__ qws, u16* __restrict__ kws, u16* __restrict__ vws)
{
    __shared__ __align__(16) u16 Ash[256 * 64];   // 32KB
    __shared__ __align__(16) u16 Bsh[128 * 64];   // 16KB
    // bijective XCD-region swizzle: xcd -> 4bm x 12bn region of the 16x24 grid
    const int id = blockIdx.x;                 // 0..383
    const int xcd = id & 7, slot = id >> 3;    // slot 0..47
    const int bm = (xcd >> 1) * 4 + (slot & 3);    // 0..15
    const int bn = (xcd & 1) * 12 + (slot >> 2);   // 0..23
    const int tid = threadIdx.x;
    const int lane = tid & 63, wid = tid >> 6;     // wid 0..7
    const int wm = wid >> 1, wn = wid & 1;         // wm 0..3, wn 0..1
    const int g = lane >> 4, lq = lane & 15;

    f32x4 acc[4][4];
#pragma unroll
    for (int i = 0; i < 4; i++)
#pragma unroll
        for (int j = 0; j < 4; j++) acc[i][j] = (f32x4){0.f, 0.f, 0.f, 0.f};

    const int lrow = lane >> 3;
    const int lchunk = (lane & 7) ^ lrow;
    const u16* Ab = X + (size_t)(bm * 256 + lrow) * 1024 + lchunk * 8;
    const u16* Bb = W + (size_t)(bn * 128 + lrow) * 1024 + lchunk * 8;

    for (int kt = 0; kt < 16; ++kt) {
#pragma unroll
        for (int i = 0; i < 4; i++) {
            int sub = wid * 4 + i;   // 0..31  (8-row sub-block of A)
            gload_lds16(Ab + (size_t)sub * 8192 + kt * 64, &Ash[sub * 512]);
        }
#pragma unroll
        for (int i = 0; i < 2; i++) {
            int sub = wid * 2 + i;   // 0..15  (8-row sub-block of B)
            gload_lds16(Bb + (size_t)sub * 8192 + kt * 64, &Bsh[sub * 512]);
        }
        __syncthreads();
#pragma unroll
        for (int ka = 0; ka < 2; ka++) {
            bf16x8 af[4], bfr[4];
#pragma unroll
            for (int mt = 0; mt < 4; mt++) {
                int row = wm * 64 + mt * 16 + lq;
                af[mt] = *(const bf16x8*)&Ash[row * 64 + (((ka * 4 + g) ^ (row & 7)) << 3)];
            }
#pragma unroll
            for (int nt = 0; nt < 4; nt++) {
                int row = wn * 64 + nt * 16 + lq;
                bfr[nt] = *(const bf16x8*)&Bsh[row * 64 + (((ka * 4 + g) ^ (row & 7)) << 3)];
            }
#pragma unroll
            for (int mt = 0; mt < 4; mt++)
#pragma unroll
                for (int nt = 0; nt < 4; nt++)
                    acc[mt][nt] = MFMA16(af[mt], bfr[nt], acc[mt][nt]);
        }
        __syncthreads();
    }

    // scatter epilogue: f -> (t, h, d); m -> (b, n)
#pragma unroll
    for (int mt = 0; mt < 4; mt++) {
#pragma unroll
        for (int nt = 0; nt < 4; nt++) {
            int f = bn * 128 + wn * 64 + nt * 16 + lq;
            int t = f >> 10, h = (f >> 6) & 15, d = f & 63;
            int mbase = bm * 256 + wm * 64 + mt * 16 + g * 4;
            int b = mbase >> 11, n0 = mbase & 2047;
            if (t == 0) {
#pragma unroll
                for (int r = 0; r < 4; r++)
                    qws[((size_t)(b * 16 + h) * 2048 + n0 + r) * 64 + d] =
                        f2bf(acc[mt][nt][r] * 0.18033688f);  // 0.125*log2(e)
            } else if (t == 1) {
#pragma unroll
                for (int r = 0; r < 4; r++)
                    kws[((size_t)(b * 16 + h) * 2048 + n0 + r) * 64 + d] =
                        f2bf(acc[mt][nt][r]);
            } else {
                ushort4 pk;
                pk.x = f2bf(acc[mt][nt][0]);
                pk.y = f2bf(acc[mt][nt][1]);
                pk.z = f2bf(acc[mt][nt][2]);
                pk.w = f2bf(acc[mt][nt][3]);
                *(ushort4*)&vws[((size_t)(b * 16 + h) * 64 + d) * 2048 + n0] = pk;
            }
        }
    }
}

// ---------------------------------------------------------------------------
// Kernel 2: flash attention, KV-split 2. Grid (32 bh, 8 qt, 2 kvh).
// 4 waves x 64 q-rows; 16 KV-tiles of 64. Double-buffered gload_lds staging,
// counted vmcnt(4). Swapped QK^T -> packed b64 P-transpose via per-wave LDS.
// Unnormalized fp32 partials + l-sums to ws (no-max softmax => plain sums).
// ---------------------------------------------------------------------------
__global__ __launch_bounds__(256, 2) void attn_kernel(
    const u16* __restrict__ qws, const u16* __restrict__ kws,
    const u16* __restrict__ vws, float* __restrict__ Opart,
    float* __restrict__ lpart)
{
    __shared__ __align__(16) u16 Ksh[2][64 * 64];   // [kv][d], chunk-swizzled
    __shared__ __align__(16) u16 Vsh[2][64 * 64];   // [d][kv], chunk-swizzled
    __shared__ __align__(16) u16 Psh[4][64 * 64];   // per-wave [q][kv], swizzled
    const int bh = blockIdx.x, qt = blockIdx.y, kvh = blockIdx.z;
    const int tid = threadIdx.x, wid = tid >> 6, lane = tid & 63;
    const int g = lane >> 4, lq = lane & 15;

    const u16* Qp = qws + ((size_t)bh * 2048 + qt * 256 + wid * 64) * 64;
    bf16x8 qf[4][2];
#pragma unroll
    for (int qa = 0; qa < 4; qa++) {
        qf[qa][0] = *(const bf16x8*)(Qp + (qa * 16 + lq) * 64 + g * 8);
        qf[qa][1] = *(const bf16x8*)(Qp + (qa * 16 + lq) * 64 + 32 + g * 8);
    }

    const int lrow = lane >> 3;            // 0..7
    const int lchunk = (lane & 7) ^ lrow;  // XOR pre-swizzle
    const u16* Kb = kws + (size_t)bh * 2048 * 64 + (size_t)lrow * 64 + lchunk * 8;
    const u16* Vb = vws + (size_t)bh * 64 * 2048 + (size_t)lrow * 2048 + lchunk * 8;

#define STAGE(TG, BUF)                                                        \
    {                                                                         \
        _Pragma("unroll")                                                     \
        for (int i = 0; i < 2; i++) {                                         \
            int sub = wid * 2 + i;                                            \
            gload_lds16(Kb + (size_t)((TG) * 64 + sub * 8) * 64,              \
                        &Ksh[BUF][sub * 512]);                                \
            gload_lds16(Vb + (size_t)(sub * 8) * 2048 + (TG) * 64,            \
                        &Vsh[BUF][sub * 512]);                                \
        }                                                                     \
    }

    bf16x8 onesB;
#pragma unroll
    for (int i = 0; i < 8; i++) onesB[i] = (short)0x3F80;

    f32x4 oacc[4][4];
#pragma unroll
    for (int qa = 0; qa < 4; qa++)
#pragma unroll
        for (int i = 0; i < 4; i++) oacc[qa][i] = (f32x4){0.f, 0.f, 0.f, 0.f};
    f32x4 lacc[4];
#pragma unroll
    for (int qa = 0; qa < 4; qa++) lacc[qa] = (f32x4){0.f, 0.f, 0.f, 0.f};

    const int tbase = kvh * 16;
    STAGE(tbase, 0);

    for (int t = 0; t < 16; ++t) {
        const int buf = t & 1;
        STAGE(tbase + ((t + 1) & 15), buf ^ 1);           // prefetch next tile
        asm volatile("s_waitcnt vmcnt(4)" ::: "memory");  // this tile's 4 done
        __builtin_amdgcn_s_barrier();
        __builtin_amdgcn_sched_barrier(0);

        // QK^T (swapped): per nt load K-frags once, reuse across 4 q-subtiles
#pragma unroll
        for (int nt = 0; nt < 4; nt++) {
            int row = nt * 16 + lq;
            bf16x8 kb0 = *(const bf16x8*)&Ksh[buf][row * 64 + ((g ^ (row & 7)) << 3)];
            bf16x8 kb1 = *(const bf16x8*)&Ksh[buf][row * 64 + (((4 + g) ^ (row & 7)) << 3)];
            int c16 = nt * 2 + (g >> 1);
#pragma unroll
            for (int qa = 0; qa < 4; qa++) {
                f32x4 z = (f32x4){0.f, 0.f, 0.f, 0.f};
                z = MFMA16(kb0, qf[qa][0], z);
                z = MFMA16(kb1, qf[qa][1], z);
#pragma unroll
                for (int r = 0; r < 4; r++) z[r] = __builtin_amdgcn_exp2f(z[r]);
                uint2 pk;
                pk.x = pk2(z[0], z[1]);
                pk.y = pk2(z[2], z[3]);
                int prow = qa * 16 + lq;
                *(uint2*)&Psh[wid][prow * 64 + (((c16 ^ (lq & 7)) << 3) | ((g & 1) << 2))] = pk;
            }
        }
        asm volatile("s_waitcnt lgkmcnt(0)" ::: "memory");
        __builtin_amdgcn_sched_barrier(0);

        // PV + rowsum, in q-subtile pairs (bounds VGPR)
        __builtin_amdgcn_s_setprio(1);
#pragma unroll
        for (int qp = 0; qp < 2; qp++) {
            bf16x8 pa[2][2];
#pragma unroll
            for (int q2 = 0; q2 < 2; q2++) {
                int prow = (qp * 2 + q2) * 16 + lq;
                pa[q2][0] = *(const bf16x8*)&Psh[wid][prow * 64 + ((g ^ (lq & 7)) << 3)];
                pa[q2][1] = *(const bf16x8*)&Psh[wid][prow * 64 + (((4 + g) ^ (lq & 7)) << 3)];
                lacc[qp * 2 + q2] = MFMA16(pa[q2][0], onesB, lacc[qp * 2 + q2]);
                lacc[qp * 2 + q2] = MFMA16(pa[q2][1], onesB, lacc[qp * 2 + q2]);
            }
#pragma unroll
            for (int dt = 0; dt < 4; dt++) {
                int vrow = dt * 16 + lq;
                bf16x8 vb0 = *(const bf16x8*)&Vsh[buf][vrow * 64 + ((g ^ (vrow & 7)) << 3)];
                bf16x8 vb1 = *(const bf16x8*)&Vsh[buf][vrow * 64 + (((4 + g) ^ (vrow & 7)) << 3)];
#pragma unroll
                for (int q2 = 0; q2 < 2; q2++) {
                    oacc[qp * 2 + q2][dt] = MFMA16(pa[q2][0], vb0, oacc[qp * 2 + q2][dt]);
                    oacc[qp * 2 + q2][dt] = MFMA16(pa[q2][1], vb1, oacc[qp * 2 + q2][dt]);
                }
            }
        }
        __builtin_amdgcn_s_setprio(0);
        asm volatile("s_waitcnt lgkmcnt(0)" ::: "memory");  // reads landed
        __builtin_amdgcn_s_barrier();                       // before overwrite
    }
#undef STAGE

    // unnormalized fp32 partials
    const int nbase = qt * 256 + wid * 64;
#pragma unroll
    for (int qa = 0; qa < 4; qa++) {
#pragma unroll
        for (int dt = 0; dt < 4; dt++)
#pragma unroll
            for (int r = 0; r < 4; r++) {
                int n = nbase + qa * 16 + g * 4 + r;
                Opart[(size_t)kvh * 4194304 + ((size_t)bh * 2048 + n) * 64 + dt * 16 + lq] =
                    oacc[qa][dt][r];
            }
        if (lq == 0) {
#pragma unroll
            for (int r = 0; r < 4; r++)
                lpart[kvh * 65536 + bh * 2048 + nbase + qa * 16 + g * 4 + r] =
                    lacc[qa][r];
        }
    }
}

// ---------------------------------------------------------------------------
// Kernel 2b: combine the two KV-half partials: O = (O0+O1)/(l0+l1) -> bf16.
// ---------------------------------------------------------------------------
__global__ __launch_bounds__(256) void combine_kernel(
    const float* __restrict__ Opart, const float* __restrict__ lpart,
    u16* __restrict__ ows)
{
    int idx = blockIdx.x * 256 + threadIdx.x;
    int d4 = (idx & 15) * 4;
    int n  = (idx >> 4) & 2047;
    int bh = idx >> 15;
    size_t o = ((size_t)bh * 2048 + n) * 64 + d4;
    float4 a = *(const float4*)(Opart + o);
    float4 c = *(const float4*)(Opart + 4194304 + o);
    float rl = 1.0f / (lpart[bh * 2048 + n] + lpart[65536 + bh * 2048 + n]);
    ushort4 pk;
    pk.x = f2bf((a.x + c.x) * rl);
    pk.y = f2bf((a.y + c.y) * rl);
    pk.z = f2bf((a.z + c.z) * rl);
    pk.w = f2bf((a.w + c.w) * rl);
    int b = bh >> 4, h = bh & 15;
    *(ushort4*)&ows[((size_t)b * 2048 + n) * 1024 + h * 64 + d4] = pk;
}

// ---------------------------------------------------------------------------
// Kernel 3: output projection. 128x128 tile, XCD-swizzled (8bm x 4bn regions).
// ---------------------------------------------------------------------------
__global__ __launch_bounds__(256) void out_gemm_kernel(
    const u16* __restrict__ A, const u16* __restrict__ W,
    const float* __restrict__ bias, float* __restrict__ Out)
{
    __shared__ __align__(16) u16 Ash[128 * 64];
    __shared__ __align__(16) u16 Bsh[128 * 64];
    // bijective XCD-region swizzle over the 32x8 grid
    const int id = blockIdx.x;                // 0..255
    const int xcd = id & 7, slot = id >> 3;   // slot 0..31
    const int bm = (xcd >> 1) * 8 + (slot & 7);   // 0..31
    const int bn = (xcd & 1) * 4 + (slot >> 3);   // 0..7
    const int tid = threadIdx.x;
    const int lane = tid & 63, wid = tid >> 6;
    const int wm = wid >> 1, wn = wid & 1;
    const int g = lane >> 4, lq = lane & 15;

    f32x4 acc[4][4];
#pragma unroll
    for (int i = 0; i < 4; i++)
#pragma unroll
        for (int j = 0; j < 4; j++) acc[i][j] = (f32x4){0.f, 0.f, 0.f, 0.f};

    const int lrow = lane >> 3;
    const int lchunk = (lane & 7) ^ lrow;
    const u16* Ab = A + (size_t)(bm * 128 + lrow) * 1024 + lchunk * 8;
    const u16* Bb = W + (size_t)(bn * 128 + lrow) * 1024 + lchunk * 8;

    for (int kt = 0; kt < 16; ++kt) {
#pragma unroll
        for (int i = 0; i < 4; i++) {
            int sub = i * 4 + wid;
            gload_lds16(Ab + (size_t)sub * 8192 + kt * 64, &Ash[sub * 512]);
            gload_lds16(Bb + (size_t)sub * 8192 + kt * 64, &Bsh[sub * 512]);
        }
        __syncthreads();
#pragma unroll
        for (int ka = 0; ka < 2; ka++) {
            bf16x8 af[4], bfr[4];
#pragma unroll
            for (int mt = 0; mt < 4; mt++) {
                int row = wm * 64 + mt * 16 + lq;
                af[mt] = *(const bf16x8*)&Ash[row * 64 + (((ka * 4 + g) ^ (row & 7)) << 3)];
            }
#pragma unroll
            for (int nt = 0; nt < 4; nt++) {
                int row = wn * 64 + nt * 16 + lq;
                bfr[nt] = *(const bf16x8*)&Bsh[row * 64 + (((ka * 4 + g) ^ (row & 7)) << 3)];
            }
#pragma unroll
            for (int mt = 0; mt < 4; mt++)
#pragma unroll
                for (int nt = 0; nt < 4; nt++)
                    acc[mt][nt] = MFMA16(af[mt], bfr[nt], acc[mt][nt]);
        }
        __syncthreads();
    }

#pragma unroll
    for (int mt = 0; mt < 4; mt++) {
#pragma unroll
        for (int nt = 0; nt < 4; nt++) {
            int ncol = bn * 128 + wn * 64 + nt * 16 + lq;
            float bv = bias[ncol];
            int mbase = bm * 128 + wm * 64 + mt * 16 + g * 4;
#pragma unroll
            for (int r = 0; r < 4; r++)
                Out[(size_t)(mbase + r) * 1024 + ncol] = acc[mt][nt][r] + bv;
        }
    }
}

extern "C" void kernel_launch(void* const* d_in, const int* in_sizes, int n_in,
                              void* d_out, int out_size, void* d_ws, size_t ws_size,
                              hipStream_t stream) {
    const float* x     = (const float*)d_in[0];  // [2,2048,1024]
    const float* w_qkv = (const float*)d_in[1];  // [3072,1024]
    const float* w_out = (const float*)d_in[2];  // [1024,1024]
    const float* b_out = (const float*)d_in[3];  // [1024]
    float* out = (float*)d_out;                  // [2,2048,1024]

    u16* xb  = (u16*)d_ws;                       // 4M elems
    u16* wqb = xb + 4194304;                     // 3M
    u16* wob = wqb + 3145728;                    // 1M
    u16* qws = wob + 1048576;                    // 4M
    u16* kws = qws + 4194304;                    // 4M
    u16* vws = kws + 4194304;                    // 4M
    u16* ows = vws + 4194304;                    // 4M
    float* Opart = (float*)(ows + 4194304);      // 8M floats (2 x 4M)
    float* lpart = Opart + 8388608;              // 128K floats

    cvt_kernel<<<4096, 256, 0, stream>>>(x, w_qkv, w_out, xb);
    qkv_gemm_kernel<<<384, 512, 0, stream>>>(xb, wqb, qws, kws, vws);
    attn_kernel<<<dim3(32, 8, 2), 256, 0, stream>>>(qws, kws, vws, Opart, lpart);
    combine_kernel<<<4096, 256, 0, stream>>>(Opart, lpart, ows);
    out_gemm_kernel<<<256, 256, 0, stream>>>(ows, wob, b_out, out);
}